// Round 21
// baseline (2381.145 us; speedup 1.0000x reference)
//
#include <hip/hip_runtime.h>
#include <hip/hip_bf16.h>

// GPT-2 small forward: L=12, H=12, E=768, V=50257, B=2, T=1024, HS=64
// fp32 in/out; internal: bf16 storage + MFMA 16x16x32, fp32 accumulate.
// R21: = R20 (best) + fc GEMM widened to BN=256 (halves A re-staging, doubles
//      MFMA per staging phase; 40KB LDS -> 4 blocks/CU). gemm2 gains BN param.

typedef __bf16 bf16x8 __attribute__((ext_vector_type(8)));
typedef float f32x4 __attribute__((ext_vector_type(4)));
typedef unsigned int u32x4 __attribute__((ext_vector_type(4)));
typedef unsigned short ushort_t;

__device__ inline unsigned short f2bf(float f) {
    unsigned int u = __float_as_uint(f);
    u += 0x7FFFu + ((u >> 16) & 1u);   // round-to-nearest-even
    return (unsigned short)(u >> 16);
}
__device__ inline unsigned int pk2(float a, float b) {
    return (unsigned int)f2bf(a) | ((unsigned int)f2bf(b) << 16);
}
__device__ inline float gelu_f(float v) {
    return 0.5f * v * (1.0f + erff(v * 0.70710678118654752f));
}
__device__ inline void gld16(const ushort_t* g, ushort_t* l) {
    __builtin_amdgcn_global_load_lds(
        (const __attribute__((address_space(1))) void*)g,
        (__attribute__((address_space(3))) void*)l, 16, 0, 0);
}
__device__ inline void store_c(float* p, float v) { *p = v; }
__device__ inline void store_c(ushort_t* p, float v) { *p = f2bf(v); }

// ------------------------------------------------- layernorm (fp32 in, bf16 out)
__device__ inline void ln_body(
    const float* __restrict__ in, const float* __restrict__ w,
    const float* __restrict__ b, ushort_t* __restrict__ out, int row) {
    const float* r = in + (size_t)row * 768;
    int tid = threadIdx.x;
    float v[3];
#pragma unroll
    for (int j = 0; j < 3; j++) v[j] = r[tid + j * 256];
    float s = v[0] + v[1] + v[2];
    __shared__ float sh1[4], sh2[4];
#pragma unroll
    for (int o = 32; o; o >>= 1) s += __shfl_down(s, o);
    if ((tid & 63) == 0) sh1[tid >> 6] = s;
    __syncthreads();
    float mean = (sh1[0] + sh1[1] + sh1[2] + sh1[3]) * (1.0f / 768.0f);
    float d0 = v[0] - mean, d1 = v[1] - mean, d2 = v[2] - mean;
    float sq = d0 * d0 + d1 * d1 + d2 * d2;
#pragma unroll
    for (int o = 32; o; o >>= 1) sq += __shfl_down(sq, o);
    if ((tid & 63) == 0) sh2[tid >> 6] = sq;
    __syncthreads();
    float var = (sh2[0] + sh2[1] + sh2[2] + sh2[3]) * (1.0f / 768.0f);
    float rstd = rsqrtf(var + 1e-5f);
#pragma unroll
    for (int j = 0; j < 3; j++) {
        int c = tid + j * 256;
        out[(size_t)row * 768 + c] = f2bf((v[j] - mean) * rstd * w[c] + b[c]);
    }
}

__global__ __launch_bounds__(256) void ln_kernel(
    const float* __restrict__ in, const float* __restrict__ w,
    const float* __restrict__ b, ushort_t* __restrict__ out) {
    ln_body(in, w, b, out, blockIdx.x);
}

// ---- weight transpose tile body: fp32[K,N] -> bf16[N,K]
__device__ inline void transpose_tile(
    const float* __restrict__ in, ushort_t* __restrict__ out,
    int N, int K, int n0, int k0) {
    __shared__ float tl[64][65];
    int tid = threadIdx.x;
    int r = tid >> 4, c = (tid & 15) * 4;
#pragma unroll
    for (int j = 0; j < 4; j++) {
        float4 v = *(const float4*)(in + (size_t)(k0 + r + j * 16) * N + n0 + c);
        tl[r + j * 16][c] = v.x; tl[r + j * 16][c + 1] = v.y;
        tl[r + j * 16][c + 2] = v.z; tl[r + j * 16][c + 3] = v.w;
    }
    __syncthreads();
    int nr = tid >> 2, kc = (tid & 3) * 16;
    unsigned int u[8];
#pragma unroll
    for (int j = 0; j < 8; j++)
        u[j] = pk2(tl[kc + 2 * j][nr], tl[kc + 2 * j + 1][nr]);
    u32x4 a = {u[0], u[1], u[2], u[3]}, b = {u[4], u[5], u[6], u[7]};
    ushort_t* op = out + (size_t)(n0 + nr) * K + k0 + kc;
    *(u32x4*)op = a;
    *(u32x4*)(op + 8) = b;
}

// ---- dispatch helper: map t in [0,1728) to one weight-transpose tile
__device__ inline void transpose_dispatch(
    int t,
    const float* __restrict__ aw, const float* __restrict__ pw,
    const float* __restrict__ fw, const float* __restrict__ fpw,
    ushort_t* __restrict__ awT, ushort_t* __restrict__ pwT,
    ushort_t* __restrict__ fwT, ushort_t* __restrict__ fpwT) {
    if (t < 432)       transpose_tile(aw,  awT,  2304, 768, (t % 36) * 64, (t / 36) * 64);
    else if (t < 576)  { t -= 432;  transpose_tile(pw,  pwT,  768,  768, (t % 12) * 64, (t / 12) * 64); }
    else if (t < 1152) { t -= 576;  transpose_tile(fw,  fwT,  3072, 768, (t % 48) * 64, (t / 48) * 64); }
    else               { t -= 1152; transpose_tile(fpw, fpwT, 768, 3072, (t % 12) * 64, (t / 12) * 64); }
}

// ---- embed + layer-0 weight transposes (blocks 0..2047 embed, 2048..3775 tr)
__global__ __launch_bounds__(256) void embed0_kernel(
    const int* __restrict__ idx, const float* __restrict__ wte,
    const float* __restrict__ wpe, float* __restrict__ x,
    const float* __restrict__ aw, const float* __restrict__ pw,
    const float* __restrict__ fw, const float* __restrict__ fpw,
    ushort_t* __restrict__ awT, ushort_t* __restrict__ pwT,
    ushort_t* __restrict__ fwT, ushort_t* __restrict__ fpwT) {
    int t = blockIdx.x;
    if (t < 2048) {
        int row = t, tt = row & 1023;
        int tok = idx[row];
        int tid = threadIdx.x;
#pragma unroll
        for (int j = 0; j < 3; j++) {
            int c = tid + j * 256;
            x[(size_t)row * 768 + c] = wte[(size_t)tok * 768 + c] + wpe[(size_t)tt * 768 + c];
        }
        return;
    }
    transpose_dispatch(t - 2048, aw, pw, fw, fpw, awT, pwT, fwT, fpwT);
}

// ---- lnf + wte->bf16 convert in one dispatch
__global__ __launch_bounds__(256) void lnfconv_kernel(
    const float* __restrict__ x, const float* __restrict__ lw,
    const float* __restrict__ lb, ushort_t* __restrict__ xn,
    const float* __restrict__ wte, ushort_t* __restrict__ wteb) {
    int t = blockIdx.x;
    if (t < 2048) { ln_body(x, lw, lb, xn, t); return; }
    const long long n8 = (50257LL * 768) / 8;
    long long i = (long long)(t - 2048) * 256 + threadIdx.x;
    long long stride = 4096LL * 256;
    for (; i < n8; i += stride) {
        const float4* s = (const float4*)(wte + i * 8);
        float4 a = s[0], b = s[1];
        u32x4 u = {pk2(a.x, a.y), pk2(a.z, a.w), pk2(b.x, b.y), pk2(b.z, b.w)};
        *(u32x4*)(wteb + i * 8) = u;
    }
}

// ---------------- fused causal flash attention + next-layer weight transposes
// blocks 0..191: attention. blocks 192..1919: transpose layer l+1 weights.
__global__ __launch_bounds__(256) void attn_tr_kernel(
    const ushort_t* __restrict__ qkvb,   // [2048][2304] bf16 (V cols unused)
    const ushort_t* __restrict__ vt,     // [24][64][1024] bf16 (d-major)
    ushort_t* __restrict__ y,            // [2048][768] bf16
    const float* __restrict__ aw, const float* __restrict__ pw,
    const float* __restrict__ fw, const float* __restrict__ fpw,
    ushort_t* __restrict__ awT, ushort_t* __restrict__ pwT,
    ushort_t* __restrict__ fwT, ushort_t* __restrict__ fpwT) {
    if (blockIdx.x >= 192) {
        transpose_dispatch(blockIdx.x - 192, aw, pw, fw, fpw, awT, pwT, fwT, fpwT);
        return;
    }
    int bid = blockIdx.x;
    int qt = 7 - (bid & 7);              // heavy tiles first within each (b,h)
    int q0 = qt * 128;
    int z = bid >> 3;
    int b = z / 12, h = z % 12;

    __shared__ __align__(16) ushort_t Ks[64 * 64];
    __shared__ __align__(16) ushort_t Vs[64 * 64];
    __shared__ __align__(16) ushort_t Ps[4][32 * 72];

    int tid = threadIdx.x;
    int lane = tid & 63, w = tid >> 6;
    int fr = lane & 15;
    int g4 = lane >> 4;
    int kg = g4 * 8;

    const ushort_t* qbase = qkvb + (size_t)b * 1024 * 2304;
    bf16x8 qf[2][2];
#pragma unroll
    for (int m = 0; m < 2; m++)
#pragma unroll
        for (int ks = 0; ks < 2; ks++)
            qf[m][ks] = *(const bf16x8*)(qbase +
                (size_t)(q0 + w * 32 + m * 16 + fr) * 2304 + h * 64 + ks * 32 + kg);

    f32x4 oacc[2][4] = {};
    float mrow[2][4], lrow[2][4];
#pragma unroll
    for (int m = 0; m < 2; m++)
#pragma unroll
        for (int i = 0; i < 4; i++) { mrow[m][i] = -1e30f; lrow[m][i] = 0.f; }

    const ushort_t* vtb = vt + (size_t)z * 64 * 1024;
    int nkt = ((q0 + 127) >> 6) + 1;
    const float LOG2E = 1.4426950408889634f;
    const float sc = 0.125f;
    int swr = (fr & 7) << 3;            // read-side XOR (ushort units)

    for (int kt = 0; kt < nkt; kt++) {
        int k0 = kt << 6;
#pragma unroll
        for (int c2 = 0; c2 < 2; c2++) {
            int c = tid + c2 * 256;
            int row = c >> 3;
            int col8 = ((c & 7) << 3) ^ ((row & 7) << 3);   // source pre-swizzle
            gld16(qbase + (size_t)(k0 + row) * 2304 + 768 + h * 64 + col8, Ks + c * 8);
            gld16(vtb + (size_t)row * 1024 + k0 + col8, Vs + c * 8);
        }
        __syncthreads();
        bool active = (k0 <= q0 + w * 32 + 31);
        if (active) {
            f32x4 s[2][4] = {};
#pragma unroll
            for (int ks = 0; ks < 2; ks++) {
                int cc = (ks * 32 + kg) ^ swr;
                bf16x8 kf[4];
#pragma unroll
                for (int n = 0; n < 4; n++)
                    kf[n] = *(const bf16x8*)(Ks + (n * 16 + fr) * 64 + cc);
#pragma unroll
                for (int m = 0; m < 2; m++)
#pragma unroll
                    for (int n = 0; n < 4; n++)
                        s[m][n] = __builtin_amdgcn_mfma_f32_16x16x32_bf16(qf[m][ks], kf[n], s[m][n], 0, 0, 0);
            }
            float al[2][4];
#pragma unroll
            for (int m = 0; m < 2; m++) {
#pragma unroll
                for (int i = 0; i < 4; i++) {
                    int q = q0 + w * 32 + m * 16 + g4 * 4 + i;
                    float pm = -1e30f;
#pragma unroll
                    for (int n = 0; n < 4; n++) {
                        int kv = k0 + n * 16 + fr;
                        float v = (kv <= q) ? s[m][n][i] * sc : -1e30f;
                        s[m][n][i] = v;
                        pm = fmaxf(pm, v);
                    }
                    pm = fmaxf(pm, __shfl_xor(pm, 1));
                    pm = fmaxf(pm, __shfl_xor(pm, 2));
                    pm = fmaxf(pm, __shfl_xor(pm, 4));
                    pm = fmaxf(pm, __shfl_xor(pm, 8));
                    float mn = fmaxf(mrow[m][i], pm);
                    float alpha = __builtin_exp2f((mrow[m][i] - mn) * LOG2E);
                    mrow[m][i] = mn;
                    al[m][i] = alpha;
                    float ps = 0.f;
#pragma unroll
                    for (int n = 0; n < 4; n++) {
                        float pv = __builtin_exp2f((s[m][n][i] - mn) * LOG2E);
                        s[m][n][i] = pv;
                        ps += pv;
                    }
                    ps += __shfl_xor(ps, 1);
                    ps += __shfl_xor(ps, 2);
                    ps += __shfl_xor(ps, 4);
                    ps += __shfl_xor(ps, 8);
                    lrow[m][i] = lrow[m][i] * alpha + ps;
                }
            }
#pragma unroll
            for (int m = 0; m < 2; m++)
#pragma unroll
                for (int nd = 0; nd < 4; nd++)
#pragma unroll
                    for (int i = 0; i < 4; i++)
                        oacc[m][nd][i] *= al[m][i];
#pragma unroll
            for (int m = 0; m < 2; m++)
#pragma unroll
                for (int n = 0; n < 4; n++)
#pragma unroll
                    for (int i = 0; i < 4; i++)
                        Ps[w][(m * 16 + g4 * 4 + i) * 72 + n * 16 + fr] = f2bf(s[m][n][i]);
        }
        __syncthreads();
        if (active) {
#pragma unroll
            for (int ks = 0; ks < 2; ks++) {
                int cc = (ks * 32 + kg) ^ swr;
                bf16x8 pa[2], vf[4];
#pragma unroll
                for (int m = 0; m < 2; m++)
                    pa[m] = *(const bf16x8*)(&Ps[w][(m * 16 + fr) * 72 + ks * 32 + kg]);
#pragma unroll
                for (int nd = 0; nd < 4; nd++)
                    vf[nd] = *(const bf16x8*)(Vs + (nd * 16 + fr) * 64 + cc);
#pragma unroll
                for (int m = 0; m < 2; m++)
#pragma unroll
                    for (int nd = 0; nd < 4; nd++)
                        oacc[m][nd] = __builtin_amdgcn_mfma_f32_16x16x32_bf16(pa[m], vf[nd], oacc[m][nd], 0, 0, 0);
            }
        }
        __syncthreads();
    }
    ushort_t* yb = y + (size_t)b * 1024 * 768 + h * 64;
#pragma unroll
    for (int m = 0; m < 2; m++)
#pragma unroll
        for (int nd = 0; nd < 4; nd++)
#pragma unroll
            for (int i = 0; i < 4; i++) {
                int q = q0 + w * 32 + m * 16 + g4 * 4 + i;
                yb[(size_t)q * 768 + nd * 16 + fr] = f2bf(oacc[m][nd][i] / lrow[m][i]);
            }
}

// ---------------------------------------------------------------- GEMM v4 + T2 swizzle
// C[M,N](+bias/gelu/residual) = A[M,K]bf16 @ B[N,K]bf16^T
// BM in {64,128}, BN in {128,256}, BK=64, 256 threads (4 waves, 2x2 wave grid;
// each wave (BM/2) x (BN/2)).
// EPI: 0=bias, 1=bias+gelu, 2=bias+residual(fp32 R),
//      3=qkv fused-V (BN=128 only): cols<1536 -> C; cols>=1536 -> LDS -> vt
template <int BM, int BN, int EPI, typename TC>
__global__ __launch_bounds__(256) void gemm2(
    const ushort_t* __restrict__ A, int lda,
    const ushort_t* __restrict__ B, int ldb,
    TC* __restrict__ C, int ldc,
    const float* __restrict__ bias, const float* __restrict__ R,
    ushort_t* __restrict__ VT,
    int M, int N, int K) {
    constexpr int MR = BM / 32;      // m-frags per wave (wave = BM/2 rows)
    constexpr int NB = BN / 32;      // B staging chunks == n-frags per wave
    int brow = blockIdx.y * BM;
    int bcol = blockIdx.x * BN;

    __shared__ __align__(16) ushort_t As[BM * 64];
    __shared__ __align__(16) ushort_t Bs[BN * 64];
    // V-transpose staging (EPI==3 only): [128 d][80 t-pad] ushorts (20.5 KB)
    __shared__ __align__(16) ushort_t Tr[EPI == 3 ? 128 * 80 : 1];

    int tid = threadIdx.x;
    int lane = tid & 63, wid = tid >> 6;
    int wr = (wid >> 1) * (BM / 2);
    int wc = (wid & 1) * (BN / 2);
    int fr = lane & 15;
    int g4 = lane >> 4;
    int kg = g4 * 8;
    int swr = (fr & 7) << 3;            // read-side XOR (ushort units)

    // staging: dest row = rg*32 + tid/8, dest k-col = (tid&7)*8; source pre-swizzled
    int colk = ((tid & 7) << 3) ^ (((tid >> 3) & 7) << 3);
    const ushort_t* Agr[MR];
    const ushort_t* Bgr[NB];
#pragma unroll
    for (int rg = 0; rg < MR; rg++)
        Agr[rg] = A + (size_t)(brow + rg * 32 + (tid >> 3)) * lda + colk;
#pragma unroll
    for (int rg = 0; rg < NB; rg++) {
        int br = bcol + rg * 32 + (tid >> 3);
        if (br > N - 1) br = N - 1;
        Bgr[rg] = B + (size_t)br * ldb + colk;
    }
    ushort_t* Al = As + tid * 8;
    ushort_t* Bl = Bs + tid * 8;

    f32x4 acc[MR][NB] = {};

    for (int k0 = 0; k0 < K; k0 += 64) {
#pragma unroll
        for (int rg = 0; rg < MR; rg++) gld16(Agr[rg] + k0, Al + rg * 2048);
#pragma unroll
        for (int rg = 0; rg < NB; rg++) gld16(Bgr[rg] + k0, Bl + rg * 2048);
        __syncthreads();
#pragma unroll
        for (int ks = 0; ks < 2; ks++) {
            int cc = (ks * 32 + kg) ^ swr;
            bf16x8 af[MR], bfv[NB];
#pragma unroll
            for (int m = 0; m < MR; m++)
                af[m] = *(const bf16x8*)(As + (wr + m * 16 + fr) * 64 + cc);
#pragma unroll
            for (int n = 0; n < NB; n++)
                bfv[n] = *(const bf16x8*)(Bs + (wc + n * 16 + fr) * 64 + cc);
#pragma unroll
            for (int m = 0; m < MR; m++)
#pragma unroll
                for (int n = 0; n < NB; n++)
                    acc[m][n] = __builtin_amdgcn_mfma_f32_16x16x32_bf16(af[m], bfv[n], acc[m][n], 0, 0, 0);
        }
        __syncthreads();
    }

    int cr = g4 * 4;

    if constexpr (EPI == 3) {
        if (bcol >= 1536) {
            // V block (BM==64, BN==128): stash bf16(acc+bias) transposed in Tr
#pragma unroll
            for (int m = 0; m < MR; m++) {
#pragma unroll
                for (int n = 0; n < NB; n++) {
                    int dl = wc + n * 16 + fr;                  // 0..127
                    float bv = bias[bcol + dl];
#pragma unroll
                    for (int i = 0; i < 4; i++) {
                        int tl = wr + m * 16 + cr + i;          // 0..63
                        Tr[dl * 80 + tl] = f2bf(acc[m][n][i] + bv);
                    }
                }
            }
            __syncthreads();
            int bb = brow >> 10, t0g = brow & 1023;
            int dbase = bcol - 1536;
#pragma unroll
            for (int j = 0; j < 4; j++) {
                int lin = tid + j * 256;                        // 0..1023
                int dl = lin >> 3, t8 = (lin & 7) * 8;
                int dg = dbase + dl;
                int h2 = dg >> 6, dd = dg & 63;
                u32x4 v = *(const u32x4*)&Tr[dl * 80 + t8];
                *(u32x4*)(VT + ((size_t)(bb * 12 + h2) * 64 + dd) * 1024 + t0g + t8) = v;
            }
            return;
        }
    }

#pragma unroll
    for (int m = 0; m < MR; m++) {
#pragma unroll
        for (int n = 0; n < NB; n++) {
            int col = bcol + wc + n * 16 + fr;
            if (col < N) {
                float bv = bias ? bias[col] : 0.0f;
#pragma unroll
                for (int i = 0; i < 4; i++) {
                    int row = brow + wr + m * 16 + cr + i;
                    float v = acc[m][n][i] + bv;
                    if constexpr (EPI == 1) v = gelu_f(v);
                    if constexpr (EPI == 2) v += R[(size_t)row * ldc + col];
                    store_c(&C[(size_t)row * ldc + col], v);
                }
            }
        }
    }
}

// ------------------------------------- lm-head GEMM (R8-proven): 256x256, 8 waves,
// BK=64, double-buffered LDS + counted-vmcnt pipeline, 1 block/CU.
__global__ __launch_bounds__(512, 1) void gemm256(
    const ushort_t* __restrict__ A, int lda,
    const ushort_t* __restrict__ B, int ldb,
    float* __restrict__ C, int ldc,
    int M, int N, int K) {
    int Rt = gridDim.x, P = gridDim.y;
    int wgid = blockIdx.x + Rt * blockIdx.y;
    int full = P >> 3;
    int thresh = full * 8 * Rt;
    int r, pp;
    if (wgid < thresh) {
        int g = wgid / (8 * Rt);
        int wi = wgid - g * (8 * Rt);
        r = wi >> 3;
        pp = g * 8 + (wi & 7);
    } else {
        int off = wgid - thresh;
        pp = full * 8 + off / Rt;
        r = off - (off / Rt) * Rt;
    }
    int brow = r * 256;
    int bcol = pp * 256;

    __shared__ __align__(16) ushort_t As[2][256 * 64];
    __shared__ __align__(16) ushort_t Bs[2][256 * 64];

    int tid = threadIdx.x;
    int lane = tid & 63, wid = tid >> 6;
    int wr = (wid >> 2) * 128;
    int wc = (wid & 3) * 64;
    int fr = lane & 15;
    int g4 = lane >> 4;
    int kg = g4 * 8;
    int swr = (fr & 7) << 3;

    int srow = tid >> 3;
    int scol = ((tid & 7) << 3) ^ ((srow & 7) << 3);
    const ushort_t* Ag[4];
    const ushort_t* Bg[4];
#pragma unroll
    for (int s = 0; s < 4; s++) {
        Ag[s] = A + (size_t)(brow + s * 64 + srow) * lda + scol;
        int br = bcol + s * 64 + srow;
        if (br > N - 1) br = N - 1;
        Bg[s] = B + (size_t)br * ldb + scol;
    }

    f32x4 acc[8][4] = {};
    int nt = K >> 6;

#pragma unroll
    for (int s = 0; s < 4; s++) {
        gld16(Ag[s], &As[0][s * 4096 + tid * 8]);
        gld16(Bg[s], &Bs[0][s * 4096 + tid * 8]);
    }

    for (int t = 0; t < nt; t++) {
        int cur = t & 1;
        if (t + 1 < nt) {
            int nxt = cur ^ 1;
            int k0 = (t + 1) << 6;
#pragma unroll
            for (int s = 0; s < 4; s++) {
                gld16(Ag[s] + k0, &As[nxt][s * 4096 + tid * 8]);
                gld16(Bg[s] + k0, &Bs[nxt][s * 4096 + tid * 8]);
            }
            asm volatile("s_waitcnt vmcnt(8)" ::: "memory");
        } else {
            asm volatile("s_waitcnt vmcnt(0)" ::: "memory");
        }
        __builtin_amdgcn_sched_barrier(0);
        __builtin_amdgcn_s_barrier();
        __builtin_amdgcn_sched_barrier(0);

        const ushort_t* Ab = &As[cur][0];
        const ushort_t* Bb = &Bs[cur][0];
#pragma unroll
        for (int ks = 0; ks < 2; ks++) {
            int cc = (ks * 32 + kg) ^ swr;
            bf16x8 af[8], bfv[4];
#pragma unroll
            for (int m = 0; m < 8; m++)
                af[m] = *(const bf16x8*)(Ab + (wr + m * 16 + fr) * 64 + cc);
#pragma unroll
            for (int n = 0; n < 4; n++)
                bfv[n] = *(const bf16x8*)(Bb + (wc + n * 16 + fr) * 64 + cc);
#pragma unroll
            for (int m = 0; m < 8; m++)
#pragma unroll
                for (int n = 0; n < 4; n++)
                    acc[m][n] = __builtin_amdgcn_mfma_f32_16x16x32_bf16(af[m], bfv[n], acc[m][n], 0, 0, 0);
        }
        asm volatile("s_waitcnt lgkmcnt(0)" ::: "memory");
        __builtin_amdgcn_sched_barrier(0);
        __builtin_amdgcn_s_barrier();
        __builtin_amdgcn_sched_barrier(0);
    }

    int cr = g4 * 4;
#pragma unroll
    for (int m = 0; m < 8; m++) {
#pragma unroll
        for (int n = 0; n < 4; n++) {
            int col = bcol + wc + n * 16 + fr;
            if (col < N) {
#pragma unroll
                for (int i = 0; i < 4; i++) {
                    int row = brow + wr + m * 16 + cr + i;
                    C[(size_t)row * ldc + col] = acc[m][n][i];
                }
            }
        }
    }
}

// ---------------------------------------------------------------- launch
extern "C" void kernel_launch(void* const* d_in, const int* in_sizes, int n_in,
                              void* d_out, int out_size, void* d_ws, size_t ws_size,
                              hipStream_t stream) {
    const int*   idx    = (const int*)d_in[0];
    const float* wte    = (const float*)d_in[1];
    const float* wpe    = (const float*)d_in[2];
    const float* ln1_w  = (const float*)d_in[3];
    const float* ln1_b  = (const float*)d_in[4];
    const float* attn_w = (const float*)d_in[5];
    const float* attn_b = (const float*)d_in[6];
    const float* proj_w = (const float*)d_in[7];
    const float* proj_b = (const float*)d_in[8];
    const float* ln2_w  = (const float*)d_in[9];
    const float* ln2_b  = (const float*)d_in[10];
    const float* fc_w   = (const float*)d_in[11];
    const float* fc_b   = (const float*)d_in[12];
    const float* fcp_w  = (const float*)d_in[13];
    const float* fcp_b  = (const float*)d_in[14];
    const float* lnf_w  = (const float*)d_in[15];
    const float* lnf_b  = (const float*)d_in[16];
    float* out = (float*)d_out;

    const size_t S_AW = (size_t)2304 * 768, S_PW = (size_t)768 * 768;
    const size_t S_FW = (size_t)3072 * 768, S_FPW = (size_t)768 * 3072;

    // workspace layout (~146 MB)
    char* p = (char*)d_ws;
    float*    x    = (float*)p;    p += (size_t)2048 * 768 * 4;
    ushort_t* xn   = (ushort_t*)p; p += (size_t)2048 * 768 * 2;
    ushort_t* qkvb = (ushort_t*)p; p += (size_t)2048 * 2304 * 2;
    ushort_t* y    = (ushort_t*)p; p += (size_t)2048 * 768 * 2;
    ushort_t* h    = (ushort_t*)p; p += (size_t)2048 * 3072 * 2;
    ushort_t* vt   = (ushort_t*)p; p += (size_t)24 * 64 * 1024 * 2;
    ushort_t* wteb = (ushort_t*)p; p += (size_t)50257 * 768 * 2;
    ushort_t* awT[2], *pwT[2], *fwT[2], *fpwT[2];
    for (int i = 0; i < 2; i++) {            // ping-pong weight buffers
        awT[i]  = (ushort_t*)p; p += S_AW * 2;
        pwT[i]  = (ushort_t*)p; p += S_PW * 2;
        fwT[i]  = (ushort_t*)p; p += S_FW * 2;
        fpwT[i] = (ushort_t*)p; p += S_FPW * 2;
    }

    // embed + layer-0 weight transposes in one dispatch
    embed0_kernel<<<3776, 256, 0, stream>>>(
        idx, wte, wpe, x,
        attn_w, proj_w, fc_w, fcp_w, awT[0], pwT[0], fwT[0], fpwT[0]);

    for (int l = 0; l < 12; l++) {
        int cb = l & 1, nb = cb ^ 1;
        ln_kernel<<<2048, 256, 0, stream>>>(x, ln1_w + l * 768, ln1_b + l * 768, xn);
        // qkv = xn @ awT^T + b; V cols transposed into vt in-epilogue (BM=64)
        gemm2<64, 128, 3, ushort_t><<<dim3(18, 32), 256, 0, stream>>>(
            xn, 768, awT[cb], 768, qkvb, 2304,
            attn_b + l * 2304, nullptr, vt, 2048, 2304, 768);
        // attention + (layers l<11) next-layer weight transposes in idle CUs
        int nblk = (l < 11) ? 1920 : 192;
        attn_tr_kernel<<<nblk, 256, 0, stream>>>(
            qkvb, vt, y,
            attn_w + (size_t)(l + 1) * S_AW, proj_w + (size_t)(l + 1) * S_PW,
            fc_w + (size_t)(l + 1) * S_FW, fcp_w + (size_t)(l + 1) * S_FPW,
            awT[nb], pwT[nb], fwT[nb], fpwT[nb]);
        // x += y @ pwT^T + b   (BM=64, BN=128: 192 blocks)
        gemm2<64, 128, 2, float><<<dim3(6, 32), 256, 0, stream>>>(
            y, 768, pwT[cb], 768, x, 768,
            proj_b + l * 768, x, nullptr, 2048, 768, 768);
        ln_kernel<<<2048, 256, 0, stream>>>(x, ln2_w + l * 768, ln2_b + l * 768, xn);
        // h = gelu(xn @ fwT^T + b)   (BM=64, BN=256: 384 blocks)
        gemm2<64, 256, 1, ushort_t><<<dim3(12, 32), 256, 0, stream>>>(
            xn, 768, fwT[cb], 768, h, 3072,
            fc_b + l * 3072, nullptr, nullptr, 2048, 3072, 768);
        // x += h @ fpwT^T + b   (BM=64, BN=128: 192 blocks)
        gemm2<64, 128, 2, float><<<dim3(6, 32), 256, 0, stream>>>(
            h, 3072, fpwT[cb], 3072, x, 768,
            fcp_b + l * 768, x, nullptr, 2048, 768, 3072);
    }

    // lnf + wte->bf16 convert in one dispatch
    lnfconv_kernel<<<6144, 256, 0, stream>>>(x, lnf_w, lnf_b, xn, wte, wteb);
    // lm-head: 256x256 pipelined GEMM, 8 row tiles x 197 col panels
    gemm256<<<dim3(8, 197), 512, 0, stream>>>(
        xn, 768, wteb, 768, out, 50257, 2048, 50257, 768);
}

// Round 22
// 2263.031 us; speedup vs baseline: 1.0522x; 1.0522x over previous
//
#include <hip/hip_runtime.h>
#include <hip/hip_bf16.h>

// GPT-2 small forward: L=12, H=12, E=768, V=50257, B=2, T=1024, HS=64
// fp32 in/out; internal: bf16 storage + MFMA 16x16x32, fp32 accumulate.
// R22: exact revert to R20/R16 (twice-reproduced best: 2264/2268us).
//      R21's BN=256 fc tile regressed (staging phase fully exposed in the
//      2-barrier structure + halved TLP). Tile-shape search exhausted.

typedef __bf16 bf16x8 __attribute__((ext_vector_type(8)));
typedef float f32x4 __attribute__((ext_vector_type(4)));
typedef unsigned int u32x4 __attribute__((ext_vector_type(4)));
typedef unsigned short ushort_t;

__device__ inline unsigned short f2bf(float f) {
    unsigned int u = __float_as_uint(f);
    u += 0x7FFFu + ((u >> 16) & 1u);   // round-to-nearest-even
    return (unsigned short)(u >> 16);
}
__device__ inline unsigned int pk2(float a, float b) {
    return (unsigned int)f2bf(a) | ((unsigned int)f2bf(b) << 16);
}
__device__ inline float gelu_f(float v) {
    return 0.5f * v * (1.0f + erff(v * 0.70710678118654752f));
}
__device__ inline void gld16(const ushort_t* g, ushort_t* l) {
    __builtin_amdgcn_global_load_lds(
        (const __attribute__((address_space(1))) void*)g,
        (__attribute__((address_space(3))) void*)l, 16, 0, 0);
}
__device__ inline void store_c(float* p, float v) { *p = v; }
__device__ inline void store_c(ushort_t* p, float v) { *p = f2bf(v); }

// ------------------------------------------------- layernorm (fp32 in, bf16 out)
__device__ inline void ln_body(
    const float* __restrict__ in, const float* __restrict__ w,
    const float* __restrict__ b, ushort_t* __restrict__ out, int row) {
    const float* r = in + (size_t)row * 768;
    int tid = threadIdx.x;
    float v[3];
#pragma unroll
    for (int j = 0; j < 3; j++) v[j] = r[tid + j * 256];
    float s = v[0] + v[1] + v[2];
    __shared__ float sh1[4], sh2[4];
#pragma unroll
    for (int o = 32; o; o >>= 1) s += __shfl_down(s, o);
    if ((tid & 63) == 0) sh1[tid >> 6] = s;
    __syncthreads();
    float mean = (sh1[0] + sh1[1] + sh1[2] + sh1[3]) * (1.0f / 768.0f);
    float d0 = v[0] - mean, d1 = v[1] - mean, d2 = v[2] - mean;
    float sq = d0 * d0 + d1 * d1 + d2 * d2;
#pragma unroll
    for (int o = 32; o; o >>= 1) sq += __shfl_down(sq, o);
    if ((tid & 63) == 0) sh2[tid >> 6] = sq;
    __syncthreads();
    float var = (sh2[0] + sh2[1] + sh2[2] + sh2[3]) * (1.0f / 768.0f);
    float rstd = rsqrtf(var + 1e-5f);
#pragma unroll
    for (int j = 0; j < 3; j++) {
        int c = tid + j * 256;
        out[(size_t)row * 768 + c] = f2bf((v[j] - mean) * rstd * w[c] + b[c]);
    }
}

__global__ __launch_bounds__(256) void ln_kernel(
    const float* __restrict__ in, const float* __restrict__ w,
    const float* __restrict__ b, ushort_t* __restrict__ out) {
    ln_body(in, w, b, out, blockIdx.x);
}

// ---- weight transpose tile body: fp32[K,N] -> bf16[N,K]
__device__ inline void transpose_tile(
    const float* __restrict__ in, ushort_t* __restrict__ out,
    int N, int K, int n0, int k0) {
    __shared__ float tl[64][65];
    int tid = threadIdx.x;
    int r = tid >> 4, c = (tid & 15) * 4;
#pragma unroll
    for (int j = 0; j < 4; j++) {
        float4 v = *(const float4*)(in + (size_t)(k0 + r + j * 16) * N + n0 + c);
        tl[r + j * 16][c] = v.x; tl[r + j * 16][c + 1] = v.y;
        tl[r + j * 16][c + 2] = v.z; tl[r + j * 16][c + 3] = v.w;
    }
    __syncthreads();
    int nr = tid >> 2, kc = (tid & 3) * 16;
    unsigned int u[8];
#pragma unroll
    for (int j = 0; j < 8; j++)
        u[j] = pk2(tl[kc + 2 * j][nr], tl[kc + 2 * j + 1][nr]);
    u32x4 a = {u[0], u[1], u[2], u[3]}, b = {u[4], u[5], u[6], u[7]};
    ushort_t* op = out + (size_t)(n0 + nr) * K + k0 + kc;
    *(u32x4*)op = a;
    *(u32x4*)(op + 8) = b;
}

// ---- dispatch helper: map t in [0,1728) to one weight-transpose tile
__device__ inline void transpose_dispatch(
    int t,
    const float* __restrict__ aw, const float* __restrict__ pw,
    const float* __restrict__ fw, const float* __restrict__ fpw,
    ushort_t* __restrict__ awT, ushort_t* __restrict__ pwT,
    ushort_t* __restrict__ fwT, ushort_t* __restrict__ fpwT) {
    if (t < 432)       transpose_tile(aw,  awT,  2304, 768, (t % 36) * 64, (t / 36) * 64);
    else if (t < 576)  { t -= 432;  transpose_tile(pw,  pwT,  768,  768, (t % 12) * 64, (t / 12) * 64); }
    else if (t < 1152) { t -= 576;  transpose_tile(fw,  fwT,  3072, 768, (t % 48) * 64, (t / 48) * 64); }
    else               { t -= 1152; transpose_tile(fpw, fpwT, 768, 3072, (t % 12) * 64, (t / 12) * 64); }
}

// ---- embed + layer-0 weight transposes (blocks 0..2047 embed, 2048..3775 tr)
__global__ __launch_bounds__(256) void embed0_kernel(
    const int* __restrict__ idx, const float* __restrict__ wte,
    const float* __restrict__ wpe, float* __restrict__ x,
    const float* __restrict__ aw, const float* __restrict__ pw,
    const float* __restrict__ fw, const float* __restrict__ fpw,
    ushort_t* __restrict__ awT, ushort_t* __restrict__ pwT,
    ushort_t* __restrict__ fwT, ushort_t* __restrict__ fpwT) {
    int t = blockIdx.x;
    if (t < 2048) {
        int row = t, tt = row & 1023;
        int tok = idx[row];
        int tid = threadIdx.x;
#pragma unroll
        for (int j = 0; j < 3; j++) {
            int c = tid + j * 256;
            x[(size_t)row * 768 + c] = wte[(size_t)tok * 768 + c] + wpe[(size_t)tt * 768 + c];
        }
        return;
    }
    transpose_dispatch(t - 2048, aw, pw, fw, fpw, awT, pwT, fwT, fpwT);
}

// ---- lnf + wte->bf16 convert in one dispatch
__global__ __launch_bounds__(256) void lnfconv_kernel(
    const float* __restrict__ x, const float* __restrict__ lw,
    const float* __restrict__ lb, ushort_t* __restrict__ xn,
    const float* __restrict__ wte, ushort_t* __restrict__ wteb) {
    int t = blockIdx.x;
    if (t < 2048) { ln_body(x, lw, lb, xn, t); return; }
    const long long n8 = (50257LL * 768) / 8;
    long long i = (long long)(t - 2048) * 256 + threadIdx.x;
    long long stride = 4096LL * 256;
    for (; i < n8; i += stride) {
        const float4* s = (const float4*)(wte + i * 8);
        float4 a = s[0], b = s[1];
        u32x4 u = {pk2(a.x, a.y), pk2(a.z, a.w), pk2(b.x, b.y), pk2(b.z, b.w)};
        *(u32x4*)(wteb + i * 8) = u;
    }
}

// ---------------- fused causal flash attention + next-layer weight transposes
// blocks 0..191: attention. blocks 192..1919: transpose layer l+1 weights.
__global__ __launch_bounds__(256) void attn_tr_kernel(
    const ushort_t* __restrict__ qkvb,   // [2048][2304] bf16 (V cols unused)
    const ushort_t* __restrict__ vt,     // [24][64][1024] bf16 (d-major)
    ushort_t* __restrict__ y,            // [2048][768] bf16
    const float* __restrict__ aw, const float* __restrict__ pw,
    const float* __restrict__ fw, const float* __restrict__ fpw,
    ushort_t* __restrict__ awT, ushort_t* __restrict__ pwT,
    ushort_t* __restrict__ fwT, ushort_t* __restrict__ fpwT) {
    if (blockIdx.x >= 192) {
        transpose_dispatch(blockIdx.x - 192, aw, pw, fw, fpw, awT, pwT, fwT, fpwT);
        return;
    }
    int bid = blockIdx.x;
    int qt = 7 - (bid & 7);              // heavy tiles first within each (b,h)
    int q0 = qt * 128;
    int z = bid >> 3;
    int b = z / 12, h = z % 12;

    __shared__ __align__(16) ushort_t Ks[64 * 64];
    __shared__ __align__(16) ushort_t Vs[64 * 64];
    __shared__ __align__(16) ushort_t Ps[4][32 * 72];

    int tid = threadIdx.x;
    int lane = tid & 63, w = tid >> 6;
    int fr = lane & 15;
    int g4 = lane >> 4;
    int kg = g4 * 8;

    const ushort_t* qbase = qkvb + (size_t)b * 1024 * 2304;
    bf16x8 qf[2][2];
#pragma unroll
    for (int m = 0; m < 2; m++)
#pragma unroll
        for (int ks = 0; ks < 2; ks++)
            qf[m][ks] = *(const bf16x8*)(qbase +
                (size_t)(q0 + w * 32 + m * 16 + fr) * 2304 + h * 64 + ks * 32 + kg);

    f32x4 oacc[2][4] = {};
    float mrow[2][4], lrow[2][4];
#pragma unroll
    for (int m = 0; m < 2; m++)
#pragma unroll
        for (int i = 0; i < 4; i++) { mrow[m][i] = -1e30f; lrow[m][i] = 0.f; }

    const ushort_t* vtb = vt + (size_t)z * 64 * 1024;
    int nkt = ((q0 + 127) >> 6) + 1;
    const float LOG2E = 1.4426950408889634f;
    const float sc = 0.125f;
    int swr = (fr & 7) << 3;            // read-side XOR (ushort units)

    for (int kt = 0; kt < nkt; kt++) {
        int k0 = kt << 6;
#pragma unroll
        for (int c2 = 0; c2 < 2; c2++) {
            int c = tid + c2 * 256;
            int row = c >> 3;
            int col8 = ((c & 7) << 3) ^ ((row & 7) << 3);   // source pre-swizzle
            gld16(qbase + (size_t)(k0 + row) * 2304 + 768 + h * 64 + col8, Ks + c * 8);
            gld16(vtb + (size_t)row * 1024 + k0 + col8, Vs + c * 8);
        }
        __syncthreads();
        bool active = (k0 <= q0 + w * 32 + 31);
        if (active) {
            f32x4 s[2][4] = {};
#pragma unroll
            for (int ks = 0; ks < 2; ks++) {
                int cc = (ks * 32 + kg) ^ swr;
                bf16x8 kf[4];
#pragma unroll
                for (int n = 0; n < 4; n++)
                    kf[n] = *(const bf16x8*)(Ks + (n * 16 + fr) * 64 + cc);
#pragma unroll
                for (int m = 0; m < 2; m++)
#pragma unroll
                    for (int n = 0; n < 4; n++)
                        s[m][n] = __builtin_amdgcn_mfma_f32_16x16x32_bf16(qf[m][ks], kf[n], s[m][n], 0, 0, 0);
            }
            float al[2][4];
#pragma unroll
            for (int m = 0; m < 2; m++) {
#pragma unroll
                for (int i = 0; i < 4; i++) {
                    int q = q0 + w * 32 + m * 16 + g4 * 4 + i;
                    float pm = -1e30f;
#pragma unroll
                    for (int n = 0; n < 4; n++) {
                        int kv = k0 + n * 16 + fr;
                        float v = (kv <= q) ? s[m][n][i] * sc : -1e30f;
                        s[m][n][i] = v;
                        pm = fmaxf(pm, v);
                    }
                    pm = fmaxf(pm, __shfl_xor(pm, 1));
                    pm = fmaxf(pm, __shfl_xor(pm, 2));
                    pm = fmaxf(pm, __shfl_xor(pm, 4));
                    pm = fmaxf(pm, __shfl_xor(pm, 8));
                    float mn = fmaxf(mrow[m][i], pm);
                    float alpha = __builtin_exp2f((mrow[m][i] - mn) * LOG2E);
                    mrow[m][i] = mn;
                    al[m][i] = alpha;
                    float ps = 0.f;
#pragma unroll
                    for (int n = 0; n < 4; n++) {
                        float pv = __builtin_exp2f((s[m][n][i] - mn) * LOG2E);
                        s[m][n][i] = pv;
                        ps += pv;
                    }
                    ps += __shfl_xor(ps, 1);
                    ps += __shfl_xor(ps, 2);
                    ps += __shfl_xor(ps, 4);
                    ps += __shfl_xor(ps, 8);
                    lrow[m][i] = lrow[m][i] * alpha + ps;
                }
            }
#pragma unroll
            for (int m = 0; m < 2; m++)
#pragma unroll
                for (int nd = 0; nd < 4; nd++)
#pragma unroll
                    for (int i = 0; i < 4; i++)
                        oacc[m][nd][i] *= al[m][i];
#pragma unroll
            for (int m = 0; m < 2; m++)
#pragma unroll
                for (int n = 0; n < 4; n++)
#pragma unroll
                    for (int i = 0; i < 4; i++)
                        Ps[w][(m * 16 + g4 * 4 + i) * 72 + n * 16 + fr] = f2bf(s[m][n][i]);
        }
        __syncthreads();
        if (active) {
#pragma unroll
            for (int ks = 0; ks < 2; ks++) {
                int cc = (ks * 32 + kg) ^ swr;
                bf16x8 pa[2], vf[4];
#pragma unroll
                for (int m = 0; m < 2; m++)
                    pa[m] = *(const bf16x8*)(&Ps[w][(m * 16 + fr) * 72 + ks * 32 + kg]);
#pragma unroll
                for (int nd = 0; nd < 4; nd++)
                    vf[nd] = *(const bf16x8*)(Vs + (nd * 16 + fr) * 64 + cc);
#pragma unroll
                for (int m = 0; m < 2; m++)
#pragma unroll
                    for (int nd = 0; nd < 4; nd++)
                        oacc[m][nd] = __builtin_amdgcn_mfma_f32_16x16x32_bf16(pa[m], vf[nd], oacc[m][nd], 0, 0, 0);
            }
        }
        __syncthreads();
    }
    ushort_t* yb = y + (size_t)b * 1024 * 768 + h * 64;
#pragma unroll
    for (int m = 0; m < 2; m++)
#pragma unroll
        for (int nd = 0; nd < 4; nd++)
#pragma unroll
            for (int i = 0; i < 4; i++) {
                int q = q0 + w * 32 + m * 16 + g4 * 4 + i;
                yb[(size_t)q * 768 + nd * 16 + fr] = f2bf(oacc[m][nd][i] / lrow[m][i]);
            }
}

// ---------------------------------------------------------------- GEMM v3 + T2 swizzle
// C[M,N](+bias/gelu/residual) = A[M,K]bf16 @ B[N,K]bf16^T
// BM=128 or 64, BN=128, BK=64, 256 threads (4 waves, each (BM/2)x64).
// EPI: 0=bias, 1=bias+gelu, 2=bias+residual(fp32 R),
//      3=qkv fused-V: cols<1536 -> C; cols>=1536 -> LDS-transpose -> vt (coalesced)
template <int BM, int EPI, typename TC>
__global__ __launch_bounds__(256) void gemm2(
    const ushort_t* __restrict__ A, int lda,
    const ushort_t* __restrict__ B, int ldb,
    TC* __restrict__ C, int ldc,
    const float* __restrict__ bias, const float* __restrict__ R,
    ushort_t* __restrict__ VT,
    int M, int N, int K) {
    constexpr int MR = BM / 32;      // A staging row-groups == m-frags per wave
    int brow = blockIdx.y * BM;
    int bcol = blockIdx.x * 128;

    __shared__ __align__(16) ushort_t As[BM * 64];
    __shared__ __align__(16) ushort_t Bs[128 * 64];
    // V-transpose staging (EPI==3 only): [128 d][80 t-pad] ushorts (20.5 KB)
    __shared__ __align__(16) ushort_t Tr[EPI == 3 ? 128 * 80 : 1];

    int tid = threadIdx.x;
    int lane = tid & 63, wid = tid >> 6;
    int wr = (wid >> 1) * (BM / 2);
    int wc = (wid & 1) * 64;
    int fr = lane & 15;
    int g4 = lane >> 4;
    int kg = g4 * 8;
    int swr = (fr & 7) << 3;            // read-side XOR (ushort units)

    // staging: dest row = rg*32 + tid/8, dest k-col = (tid&7)*8; source pre-swizzled
    int colk = ((tid & 7) << 3) ^ (((tid >> 3) & 7) << 3);
    const ushort_t* Agr[MR];
    const ushort_t* Bgr[4];
#pragma unroll
    for (int rg = 0; rg < MR; rg++)
        Agr[rg] = A + (size_t)(brow + rg * 32 + (tid >> 3)) * lda + colk;
#pragma unroll
    for (int rg = 0; rg < 4; rg++) {
        int br = bcol + rg * 32 + (tid >> 3);
        if (br > N - 1) br = N - 1;
        Bgr[rg] = B + (size_t)br * ldb + colk;
    }
    ushort_t* Al = As + tid * 8;
    ushort_t* Bl = Bs + tid * 8;

    f32x4 acc[MR][4] = {};

    for (int k0 = 0; k0 < K; k0 += 64) {
#pragma unroll
        for (int rg = 0; rg < MR; rg++) gld16(Agr[rg] + k0, Al + rg * 2048);
#pragma unroll
        for (int rg = 0; rg < 4; rg++) gld16(Bgr[rg] + k0, Bl + rg * 2048);
        __syncthreads();
#pragma unroll
        for (int ks = 0; ks < 2; ks++) {
            int cc = (ks * 32 + kg) ^ swr;
            bf16x8 af[MR], bfv[4];
#pragma unroll
            for (int m = 0; m < MR; m++)
                af[m] = *(const bf16x8*)(As + (wr + m * 16 + fr) * 64 + cc);
#pragma unroll
            for (int n = 0; n < 4; n++)
                bfv[n] = *(const bf16x8*)(Bs + (wc + n * 16 + fr) * 64 + cc);
#pragma unroll
            for (int m = 0; m < MR; m++)
#pragma unroll
                for (int n = 0; n < 4; n++)
                    acc[m][n] = __builtin_amdgcn_mfma_f32_16x16x32_bf16(af[m], bfv[n], acc[m][n], 0, 0, 0);
        }
        __syncthreads();
    }

    int cr = g4 * 4;

    if constexpr (EPI == 3) {
        if (bcol >= 1536) {
            // V block (BM==64): stash bf16(acc+bias) transposed into Tr[d][t]
#pragma unroll
            for (int m = 0; m < MR; m++) {
#pragma unroll
                for (int n = 0; n < 4; n++) {
                    int dl = wc + n * 16 + fr;                  // 0..127
                    float bv = bias[bcol + dl];
#pragma unroll
                    for (int i = 0; i < 4; i++) {
                        int tl = wr + m * 16 + cr + i;          // 0..63
                        Tr[dl * 80 + tl] = f2bf(acc[m][n][i] + bv);
                    }
                }
            }
            __syncthreads();
            int bb = brow >> 10, t0g = brow & 1023;
            int dbase = bcol - 1536;
#pragma unroll
            for (int j = 0; j < 4; j++) {
                int lin = tid + j * 256;                        // 0..1023
                int dl = lin >> 3, t8 = (lin & 7) * 8;
                int dg = dbase + dl;
                int h2 = dg >> 6, dd = dg & 63;
                u32x4 v = *(const u32x4*)&Tr[dl * 80 + t8];
                *(u32x4*)(VT + ((size_t)(bb * 12 + h2) * 64 + dd) * 1024 + t0g + t8) = v;
            }
            return;
        }
    }

#pragma unroll
    for (int m = 0; m < MR; m++) {
#pragma unroll
        for (int n = 0; n < 4; n++) {
            int col = bcol + wc + n * 16 + fr;
            if (col < N) {
                float bv = bias ? bias[col] : 0.0f;
#pragma unroll
                for (int i = 0; i < 4; i++) {
                    int row = brow + wr + m * 16 + cr + i;
                    float v = acc[m][n][i] + bv;
                    if constexpr (EPI == 1) v = gelu_f(v);
                    if constexpr (EPI == 2) v += R[(size_t)row * ldc + col];
                    store_c(&C[(size_t)row * ldc + col], v);
                }
            }
        }
    }
}

// ------------------------------------- lm-head GEMM (R8-proven): 256x256, 8 waves,
// BK=64, double-buffered LDS + counted-vmcnt pipeline, 1 block/CU.
__global__ __launch_bounds__(512, 1) void gemm256(
    const ushort_t* __restrict__ A, int lda,
    const ushort_t* __restrict__ B, int ldb,
    float* __restrict__ C, int ldc,
    int M, int N, int K) {
    int Rt = gridDim.x, P = gridDim.y;
    int wgid = blockIdx.x + Rt * blockIdx.y;
    int full = P >> 3;
    int thresh = full * 8 * Rt;
    int r, pp;
    if (wgid < thresh) {
        int g = wgid / (8 * Rt);
        int wi = wgid - g * (8 * Rt);
        r = wi >> 3;
        pp = g * 8 + (wi & 7);
    } else {
        int off = wgid - thresh;
        pp = full * 8 + off / Rt;
        r = off - (off / Rt) * Rt;
    }
    int brow = r * 256;
    int bcol = pp * 256;

    __shared__ __align__(16) ushort_t As[2][256 * 64];
    __shared__ __align__(16) ushort_t Bs[2][256 * 64];

    int tid = threadIdx.x;
    int lane = tid & 63, wid = tid >> 6;
    int wr = (wid >> 2) * 128;
    int wc = (wid & 3) * 64;
    int fr = lane & 15;
    int g4 = lane >> 4;
    int kg = g4 * 8;
    int swr = (fr & 7) << 3;

    int srow = tid >> 3;
    int scol = ((tid & 7) << 3) ^ ((srow & 7) << 3);
    const ushort_t* Ag[4];
    const ushort_t* Bg[4];
#pragma unroll
    for (int s = 0; s < 4; s++) {
        Ag[s] = A + (size_t)(brow + s * 64 + srow) * lda + scol;
        int br = bcol + s * 64 + srow;
        if (br > N - 1) br = N - 1;
        Bg[s] = B + (size_t)br * ldb + scol;
    }

    f32x4 acc[8][4] = {};
    int nt = K >> 6;

#pragma unroll
    for (int s = 0; s < 4; s++) {
        gld16(Ag[s], &As[0][s * 4096 + tid * 8]);
        gld16(Bg[s], &Bs[0][s * 4096 + tid * 8]);
    }

    for (int t = 0; t < nt; t++) {
        int cur = t & 1;
        if (t + 1 < nt) {
            int nxt = cur ^ 1;
            int k0 = (t + 1) << 6;
#pragma unroll
            for (int s = 0; s < 4; s++) {
                gld16(Ag[s] + k0, &As[nxt][s * 4096 + tid * 8]);
                gld16(Bg[s] + k0, &Bs[nxt][s * 4096 + tid * 8]);
            }
            asm volatile("s_waitcnt vmcnt(8)" ::: "memory");
        } else {
            asm volatile("s_waitcnt vmcnt(0)" ::: "memory");
        }
        __builtin_amdgcn_sched_barrier(0);
        __builtin_amdgcn_s_barrier();
        __builtin_amdgcn_sched_barrier(0);

        const ushort_t* Ab = &As[cur][0];
        const ushort_t* Bb = &Bs[cur][0];
#pragma unroll
        for (int ks = 0; ks < 2; ks++) {
            int cc = (ks * 32 + kg) ^ swr;
            bf16x8 af[8], bfv[4];
#pragma unroll
            for (int m = 0; m < 8; m++)
                af[m] = *(const bf16x8*)(Ab + (wr + m * 16 + fr) * 64 + cc);
#pragma unroll
            for (int n = 0; n < 4; n++)
                bfv[n] = *(const bf16x8*)(Bb + (wc + n * 16 + fr) * 64 + cc);
#pragma unroll
            for (int m = 0; m < 8; m++)
#pragma unroll
                for (int n = 0; n < 4; n++)
                    acc[m][n] = __builtin_amdgcn_mfma_f32_16x16x32_bf16(af[m], bfv[n], acc[m][n], 0, 0, 0);
        }
        asm volatile("s_waitcnt lgkmcnt(0)" ::: "memory");
        __builtin_amdgcn_sched_barrier(0);
        __builtin_amdgcn_s_barrier();
        __builtin_amdgcn_sched_barrier(0);
    }

    int cr = g4 * 4;
#pragma unroll
    for (int m = 0; m < 8; m++) {
#pragma unroll
        for (int n = 0; n < 4; n++) {
            int col = bcol + wc + n * 16 + fr;
            if (col < N) {
#pragma unroll
                for (int i = 0; i < 4; i++) {
                    int row = brow + wr + m * 16 + cr + i;
                    C[(size_t)row * ldc + col] = acc[m][n][i];
                }
            }
        }
    }
}

// ---------------------------------------------------------------- launch
extern "C" void kernel_launch(void* const* d_in, const int* in_sizes, int n_in,
                              void* d_out, int out_size, void* d_ws, size_t ws_size,
                              hipStream_t stream) {
    const int*   idx    = (const int*)d_in[0];
    const float* wte    = (const float*)d_in[1];
    const float* wpe    = (const float*)d_in[2];
    const float* ln1_w  = (const float*)d_in[3];
    const float* ln1_b  = (const float*)d_in[4];
    const float* attn_w = (const float*)d_in[5];
    const float* attn_b = (const float*)d_in[6];
    const float* proj_w = (const float*)d_in[7];
    const float* proj_b = (const float*)d_in[8];
    const float* ln2_w  = (const float*)d_in[9];
    const float* ln2_b  = (const float*)d_in[10];
    const float* fc_w   = (const float*)d_in[11];
    const float* fc_b   = (const float*)d_in[12];
    const float* fcp_w  = (const float*)d_in[13];
    const float* fcp_b  = (const float*)d_in[14];
    const float* lnf_w  = (const float*)d_in[15];
    const float* lnf_b  = (const float*)d_in[16];
    float* out = (float*)d_out;

    const size_t S_AW = (size_t)2304 * 768, S_PW = (size_t)768 * 768;
    const size_t S_FW = (size_t)3072 * 768, S_FPW = (size_t)768 * 3072;

    // workspace layout (~146 MB)
    char* p = (char*)d_ws;
    float*    x    = (float*)p;    p += (size_t)2048 * 768 * 4;
    ushort_t* xn   = (ushort_t*)p; p += (size_t)2048 * 768 * 2;
    ushort_t* qkvb = (ushort_t*)p; p += (size_t)2048 * 2304 * 2;
    ushort_t* y    = (ushort_t*)p; p += (size_t)2048 * 768 * 2;
    ushort_t* h    = (ushort_t*)p; p += (size_t)2048 * 3072 * 2;
    ushort_t* vt   = (ushort_t*)p; p += (size_t)24 * 64 * 1024 * 2;
    ushort_t* wteb = (ushort_t*)p; p += (size_t)50257 * 768 * 2;
    ushort_t* awT[2], *pwT[2], *fwT[2], *fpwT[2];
    for (int i = 0; i < 2; i++) {            // ping-pong weight buffers
        awT[i]  = (ushort_t*)p; p += S_AW * 2;
        pwT[i]  = (ushort_t*)p; p += S_PW * 2;
        fwT[i]  = (ushort_t*)p; p += S_FW * 2;
        fpwT[i] = (ushort_t*)p; p += S_FPW * 2;
    }

    // embed + layer-0 weight transposes in one dispatch
    embed0_kernel<<<3776, 256, 0, stream>>>(
        idx, wte, wpe, x,
        attn_w, proj_w, fc_w, fcp_w, awT[0], pwT[0], fwT[0], fpwT[0]);

    for (int l = 0; l < 12; l++) {
        int cb = l & 1, nb = cb ^ 1;
        ln_kernel<<<2048, 256, 0, stream>>>(x, ln1_w + l * 768, ln1_b + l * 768, xn);
        // qkv = xn @ awT^T + b; V cols transposed into vt in-epilogue (BM=64)
        gemm2<64, 3, ushort_t><<<dim3(18, 32), 256, 0, stream>>>(
            xn, 768, awT[cb], 768, qkvb, 2304,
            attn_b + l * 2304, nullptr, vt, 2048, 2304, 768);
        // attention + (layers l<11) next-layer weight transposes in idle CUs
        int nblk = (l < 11) ? 1920 : 192;
        attn_tr_kernel<<<nblk, 256, 0, stream>>>(
            qkvb, vt, y,
            attn_w + (size_t)(l + 1) * S_AW, proj_w + (size_t)(l + 1) * S_PW,
            fc_w + (size_t)(l + 1) * S_FW, fcp_w + (size_t)(l + 1) * S_FPW,
            awT[nb], pwT[nb], fwT[nb], fpwT[nb]);
        // x += y @ pwT^T + b   (BM=64: 192 blocks)
        gemm2<64, 2, float><<<dim3(6, 32), 256, 0, stream>>>(
            y, 768, pwT[cb], 768, x, 768,
            proj_b + l * 768, x, nullptr, 2048, 768, 768);
        ln_kernel<<<2048, 256, 0, stream>>>(x, ln2_w + l * 768, ln2_b + l * 768, xn);
        // h = gelu(xn @ fwT^T + b)   (BM=64: 768 blocks)
        gemm2<64, 1, ushort_t><<<dim3(24, 32), 256, 0, stream>>>(
            xn, 768, fwT[cb], 768, h, 3072,
            fc_b + l * 3072, nullptr, nullptr, 2048, 3072, 768);
        // x += h @ fpwT^T + b   (BM=64: 192 blocks)
        gemm2<64, 2, float><<<dim3(6, 32), 256, 0, stream>>>(
            h, 3072, fpwT[cb], 3072, x, 768,
            fcp_b + l * 768, x, nullptr, 2048, 768, 3072);
    }

    // lnf + wte->bf16 convert in one dispatch
    lnfconv_kernel<<<6144, 256, 0, stream>>>(x, lnf_w, lnf_b, xn, wte, wteb);
    // lm-head: 256x256 pipelined GEMM, 8 row tiles x 197 col panels
    gemm256<<<dim3(8, 197), 512, 0, stream>>>(
        xn, 768, wteb, 768, out, 50257, 2048, 50257, 768);
}